// Round 1
// baseline (76.348 us; speedup 1.0000x reference)
//
#include <hip/hip_runtime.h>

// SeparationLoss: mean over B of sum_{i!=j} max(0, thr^2 - ||kp_i - kp_j||^2)
// B = 131072, J = 17, 3 floats per joint -> 51 floats per batch.

#define NJ      17
#define KPF     51          // floats per batch (17*3)
#define BPB     256         // batches per block
#define THREADS 256

__global__ __launch_bounds__(THREADS)
void sep_loss_kernel(const float* __restrict__ kps,
                     float* __restrict__ out,
                     int B, float thr2, float invB) {
    __shared__ float lds[BPB * KPF];            // 52224 B
    __shared__ float wsum[THREADS / 64];

    const int tid = threadIdx.x;
    const long long b0 = (long long)blockIdx.x * BPB;

    // ---- Stage this block's 256 batches (contiguous, 16B-aligned: 256*51*4 = 13056 B per block) ----
    const float4* __restrict__ src4 =
        reinterpret_cast<const float4*>(kps + b0 * KPF);
    float4* dst4 = reinterpret_cast<float4*>(lds);
    const int n4 = BPB * KPF / 4;               // 3264 float4s
    for (int i = tid; i < n4; i += THREADS) dst4[i] = src4[i];
    __syncthreads();

    // ---- Each thread: one batch. Stride 51 (odd) -> benign LDS banking. ----
    float kp[KPF];
    const float* my = lds + tid * KPF;
    #pragma unroll
    for (int k = 0; k < KPF; ++k) kp[k] = my[k];

    float acc = 0.0f;
    #pragma unroll
    for (int i = 0; i < NJ; ++i) {
        #pragma unroll
        for (int j = i + 1; j < NJ; ++j) {
            float dx = kp[i * 3 + 0] - kp[j * 3 + 0];
            float dy = kp[i * 3 + 1] - kp[j * 3 + 1];
            float dz = kp[i * 3 + 2] - kp[j * 3 + 2];
            float d2 = fmaf(dx, dx, fmaf(dy, dy, dz * dz));
            acc += fmaxf(thr2 - d2, 0.0f);
        }
    }
    acc *= 2.0f;    // unordered -> ordered pairs

    // ---- Wave-64 reduction ----
    #pragma unroll
    for (int off = 32; off > 0; off >>= 1)
        acc += __shfl_down(acc, off, 64);
    if ((tid & 63) == 0) wsum[tid >> 6] = acc;
    __syncthreads();

    if (tid == 0) {
        float s = 0.0f;
        #pragma unroll
        for (int w = 0; w < THREADS / 64; ++w) s += wsum[w];
        atomicAdd(out, s * invB);   // device-scope by default on CDNA
    }
}

extern "C" void kernel_launch(void* const* d_in, const int* in_sizes, int n_in,
                              void* d_out, int out_size, void* d_ws, size_t ws_size,
                              hipStream_t stream) {
    const float* kps = (const float*)d_in[0];
    float* out = (float*)d_out;

    const int B = in_sizes[0] / KPF;            // 131072
    const float thr2 = 0.1f * 0.1f;             // THRESHOLD^2
    const float invB = 1.0f / (float)B;

    // d_out is poisoned with 0xAA before every timed launch -> zero it.
    hipMemsetAsync(d_out, 0, out_size * sizeof(float), stream);

    const int grid = B / BPB;                   // 512 (B divides exactly)
    sep_loss_kernel<<<grid, THREADS, 0, stream>>>(kps, out, B, thr2, invB);
}